// Round 2
// 190.207 us; speedup vs baseline: 1.0167x; 1.0167x over previous
//
#include <hip/hip_runtime.h>
#include <math.h>

namespace {
constexpr int BATCH = 4;
constexpr int DDIM  = 128;
constexpr int HDIM  = 192;
constexpr int WDIM  = 192;
constexpr long long NTOT = (long long)BATCH * DDIM * HDIM * WDIM; // 18,874,368
constexpr int NDSC  = 4 * 1 * 8 * 12 * 12;                        // 4608

constexpr int HT     = 12;              // h rows computed per block tile
constexpr int DT     = 16;              // d planes computed per block
constexpr int ROWS   = HT + 2;          // 14 slab rows: h0-1 .. h0+HT (clamped)
constexpr int SLABF  = ROWS * WDIM;     // 2688 floats per tensor per slab
constexpr int SLAB2  = 2 * SLABF;       // 5376 floats per slab (y then p)
constexpr int BLOCKV = 192;             // 16 threads/row x 12 rows = 3 waves
constexpr int GRIDV  = BATCH * (DDIM / DT) * (HDIM / HT); // 4*8*16 = 512 = 2/CU
constexpr int UPW    = 7;               // 1024B units per wave per slab (21 total, exact)
constexpr int PLSTR  = HDIM * WDIM;     // 36,864 floats per plane
constexpr int BLOCKF = 256;
}

// gd contribution: (|dy|*s - |dp|*s)^2 == s^2 * (|dy|-|dp|)^2, s2 in {1, 0.25}
#define GTERM(dy, dp, s2) { float t0_ = fabsf(dy) - fabsf(dp); gd = fmaf(t0_ * t0_, (s2), gd); }

// Stage one plane-slab as 21 flat 1024B units (64 lanes x 16B each -- the
// HW-verified global_load_lds width). Per-lane SOURCE addresses (precomputed
// in sr[]) carry the row decode + h-clamping; LDS dest is linear wave-uniform.
#define STAGE(buf, plane)                                                      \
    {                                                                          \
        const int poff_ = (plane) * PLSTR;                                     \
        _Pragma("unroll")                                                      \
        for (int k = 0; k < UPW; ++k) {                                        \
            __builtin_amdgcn_global_load_lds(                                  \
                (const __attribute__((address_space(1))) void*)(sr[k] + poff_),\
                (__attribute__((address_space(3))) void*)(                     \
                    &slab[buf][0] + (wv * UPW + k) * 256),                     \
                16, 0, 0);                                                     \
        }                                                                      \
    }

__global__ __launch_bounds__(BLOCKV) void vol_kernel(const float* __restrict__ p,
                                                     const float* __restrict__ y,
                                                     float* __restrict__ part) {
    __shared__ float slab[3][SLAB2];      // 64,512 B ring of 3 plane-slabs
    __shared__ float red[2][3];

    const int tid  = threadIdx.x;
    const int wv   = tid >> 6;
    const int lane = tid & 63;
    const int r    = tid >> 4;            // 0..11  (row within tile)
    const int i16  = tid & 15;            // 0..15  (16 threads per row)
    const int w0   = i16 * 12;            // 12 consecutive w per thread

    const int blk = blockIdx.x;
    const int ht = blk & 15;
    const int dc = (blk >> 4) & 7;
    const int b  = blk >> 7;
    const int h0 = ht * HT;
    const int d0 = dc * DT;
    const int h  = h0 + r;

    // ---- per-lane source descriptors for this wave's 7 units (at plane 0) ----
    // unit u covers slab floats [u*256, u*256+256); lane L owns fi = u*256+L*4.
    // fi < SLABF -> tensor y, else p; row = fj/192 (16B chunks never straddle a
    // row: 192 % 4 == 0; nor the y/p boundary: 2688 splits at lane 32 exactly).
    const float* sr[UPW];
    #pragma unroll
    for (int k = 0; k < UPW; ++k) {
        const int u   = wv * UPW + k;
        const int fi  = u * 256 + lane * 4;
        const int ts  = fi >= SLABF;
        const int fj  = ts ? fi - SLABF : fi;
        const int row = fj / WDIM;
        const int col = fj - row * WDIM;
        int hrow = h0 - 1 + row;
        hrow = hrow < 0 ? 0 : (hrow > HDIM - 1 ? HDIM - 1 : hrow);
        sr[k] = (ts ? p : y) + (b * DDIM * HDIM + hrow) * WDIM + col;
    }

    // ---- prologue: per-thread centers of planes clamp(d0-1) and d0 into regs ----
    float4 ym[2][3], yc[2][3];
    {
        const int pmz = d0 ? d0 - 1 : 0;
        const int om = ((b * DDIM + pmz) * HDIM + h) * WDIM + w0;
        const int oc = ((b * DDIM + d0 ) * HDIM + h) * WDIM + w0;
        #pragma unroll
        for (int g = 0; g < 3; ++g) {
            ym[0][g] = *(const float4*)(y + om + 4 * g);
            ym[1][g] = *(const float4*)(p + om + 4 * g);
            yc[0][g] = *(const float4*)(y + oc + 4 * g);
            yc[1][g] = *(const float4*)(p + oc + 4 * g);
        }
    }
    // ---- prologue: stage slabs for planes d0, d0+1, d0+2 (d0+2 <= 114) ----
    STAGE(0, d0);
    STAGE(1, d0 + 1);
    STAGE(2, d0 + 2);

    float l1 = 0.f, gd = 0.f;
    const float s2h  = (h == 0 || h == HDIM - 1) ? 1.f : 0.25f;
    const float s2w0 = (i16 == 0)  ? 1.f : 0.25f;
    const float s2w3 = (i16 == 15) ? 1.f : 0.25f;

    int cur = 0;
    #pragma unroll 1
    for (int i = 0; i < DT; ++i) {
        const int e = d0 + i;
        // Counted wait: the newest UPW outstanding per wave = slab(e+2); all
        // older batches (incl. slab(e+1), read as 'ns' below) are complete.
        // Last iter: slab(e+1) is itself the newest -> full drain.
        if (i == DT - 1) { asm volatile("s_waitcnt vmcnt(0)" ::: "memory"); }
        else             { asm volatile("s_waitcnt vmcnt(7)" ::: "memory"); }
        __builtin_amdgcn_sched_barrier(0);
        __builtin_amdgcn_s_barrier();     // acquire: all waves' DMA for e,e+1 done
        __builtin_amdgcn_sched_barrier(0);

        const int nxt = (cur == 2) ? 0 : cur + 1;
        const float* cs = &slab[cur][0];  // plane e   (h/w neighbors)
        const float* ns = &slab[nxt][0];  // plane e+1 (centers -> next yc)
        const float s2d = (e == 0 || e == DDIM - 1) ? 1.f : 0.25f;

        const int rowc = (r + 1) * WDIM;
        const float wlY = cs[rowc + (i16 ? w0 - 1 : 0)];
        const float wrY = cs[rowc + (i16 < 15 ? w0 + 12 : WDIM - 1)];
        const float wlP = cs[SLABF + rowc + (i16 ? w0 - 1 : 0)];
        const float wrP = cs[SLABF + rowc + (i16 < 15 ? w0 + 12 : WDIM - 1)];

        float4 cn[2][3];
        #pragma unroll
        for (int g = 0; g < 3; ++g) {
            const int off = w0 + 4 * g;
            const float4 cny = *(const float4*)&ns[rowc + off];
            const float4 cnp = *(const float4*)&ns[SLABF + rowc + off];
            const float4 hmy = *(const float4*)&cs[r * WDIM + off];
            const float4 hpy = *(const float4*)&cs[(r + 2) * WDIM + off];
            const float4 hmp = *(const float4*)&cs[SLABF + r * WDIM + off];
            const float4 hpp = *(const float4*)&cs[SLABF + (r + 2) * WDIM + off];
            cn[0][g] = cny; cn[1][g] = cnp;
            const float4 ay = yc[0][g], ap = yc[1][g];
            const float4 my = ym[0][g], mp = ym[1][g];

            // L1
            l1 += fabsf(ay.x - ap.x) + fabsf(ay.y - ap.y)
                + fabsf(ay.z - ap.z) + fabsf(ay.w - ap.w);
            // H axis
            GTERM(hpy.x - hmy.x, hpp.x - hmp.x, s2h);
            GTERM(hpy.y - hmy.y, hpp.y - hmp.y, s2h);
            GTERM(hpy.z - hmy.z, hpp.z - hmp.z, s2h);
            GTERM(hpy.w - hmy.w, hpp.w - hmp.w, s2h);
            // D axis (register pipeline + next-slab centers)
            GTERM(cny.x - my.x, cnp.x - mp.x, s2d);
            GTERM(cny.y - my.y, cnp.y - mp.y, s2d);
            GTERM(cny.z - my.z, cnp.z - mp.z, s2d);
            GTERM(cny.w - my.w, cnp.w - mp.w, s2d);
        }
        // W axis: 12 consecutive elements, from registers + 2 LDS edge scalars
        {
            const float4 a0 = yc[0][0], a1 = yc[0][1], a2 = yc[0][2];
            const float4 p0 = yc[1][0], p1 = yc[1][1], p2 = yc[1][2];
            GTERM(a0.y - wlY , p0.y - wlP , s2w0);
            GTERM(a0.z - a0.x, p0.z - p0.x, 0.25f);
            GTERM(a0.w - a0.y, p0.w - p0.y, 0.25f);
            GTERM(a1.x - a0.z, p1.x - p0.z, 0.25f);
            GTERM(a1.y - a0.w, p1.y - p0.w, 0.25f);
            GTERM(a1.z - a1.x, p1.z - p1.x, 0.25f);
            GTERM(a1.w - a1.y, p1.w - p1.y, 0.25f);
            GTERM(a2.x - a1.z, p2.x - p1.z, 0.25f);
            GTERM(a2.y - a1.w, p2.y - p1.w, 0.25f);
            GTERM(a2.z - a2.x, p2.z - p2.x, 0.25f);
            GTERM(a2.w - a2.y, p2.w - p2.y, 0.25f);
            GTERM(wrY  - a2.z, wrP  - p2.z, s2w3);
        }
        // shift register D-pipeline
        #pragma unroll
        for (int g = 0; g < 3; ++g) {
            ym[0][g] = yc[0][g]; ym[1][g] = yc[1][g];
            yc[0][g] = cn[0][g]; yc[1][g] = cn[1][g];
        }

        // release: every wave's ds_reads of slab(e) retired before any wave
        // may overwrite that buffer with new DMA.
        __builtin_amdgcn_sched_barrier(0);
        asm volatile("s_waitcnt lgkmcnt(0)" ::: "memory");
        __builtin_amdgcn_sched_barrier(0);
        __builtin_amdgcn_s_barrier();
        __builtin_amdgcn_sched_barrier(0);
        if (i <= DT - 3) {                // stage slab(e+3) into freed buffer
            int pl = d0 + i + 3; if (pl > DDIM - 1) pl = DDIM - 1;
            STAGE(cur, pl);
        }
        cur = nxt;
    }

    // ---- block reduction: 3 waves -> one partial pair per block ----
    #pragma unroll
    for (int off = 32; off > 0; off >>= 1) {
        l1 += __shfl_down(l1, off, 64);
        gd += __shfl_down(gd, off, 64);
    }
    if (lane == 0) { red[0][wv] = l1; red[1][wv] = gd; }
    __syncthreads();
    if (tid == 0) {
        part[2 * blk]     = red[0][0] + red[0][1] + red[0][2];
        part[2 * blk + 1] = red[1][0] + red[1][1] + red[1][2];
    }
}

// Reduce per-block partials + BCE over the small discriminator tensor.
__global__ __launch_bounds__(BLOCKF) void finalize_kernel(const float* __restrict__ dsc,
                                                          const float* __restrict__ part,
                                                          float* __restrict__ out) {
    float l1 = 0.f, gd = 0.f, s = 0.f;
    for (int i = threadIdx.x; i < GRIDV; i += BLOCKF) {
        l1 += part[2 * i];
        gd += part[2 * i + 1];
    }
    for (int i = threadIdx.x; i < NDSC; i += BLOCKF) {
        const float x = dsc[i];
        // target is zeros: max(x,0) - x*0 + log1p(exp(-|x|))
        s += fmaxf(x, 0.f) + log1pf(expf(-fabsf(x)));
    }
    __shared__ float a[4], c[4], e2[4];
    #pragma unroll
    for (int off = 32; off > 0; off >>= 1) {
        l1 += __shfl_down(l1, off, 64);
        gd += __shfl_down(gd, off, 64);
        s  += __shfl_down(s,  off, 64);
    }
    if ((threadIdx.x & 63) == 0) {
        const int w = threadIdx.x >> 6;
        a[w] = l1; c[w] = gd; e2[w] = s;
    }
    __syncthreads();
    if (threadIdx.x == 0) {
        const float bce = (e2[0] + e2[1] + e2[2] + e2[3]) / (float)NDSC;
        const float l1m = (a[0] + a[1] + a[2] + a[3]) / (float)NTOT;
        const float gdm = (c[0] + c[1] + c[2] + c[3]) / (float)NTOT;
        out[0] = bce + 100.f * (l1m + gdm);
    }
}

extern "C" void kernel_launch(void* const* d_in, const int* in_sizes, int n_in,
                              void* d_out, int out_size, void* d_ws, size_t ws_size,
                              hipStream_t stream) {
    const float* dsc_fake = (const float*)d_in[0];
    const float* predicts = (const float*)d_in[1];
    const float* y_data   = (const float*)d_in[2];
    // d_in[3] (zeros) unused: target==0 makes the -x*target term vanish.
    float* part = (float*)d_ws;   // GRIDV*2 floats, fully overwritten each call
    float* out  = (float*)d_out;

    vol_kernel<<<GRIDV, BLOCKV, 0, stream>>>(predicts, y_data, part);
    finalize_kernel<<<1, BLOCKF, 0, stream>>>(dsc_fake, part, out);
}